// Round 7
// baseline (34.968 us; speedup 1.0000x reference)
//
#include <hip/hip_runtime.h>

#define NCLS   80
#define NB     8
#define NGT    32
#define NANCH  36864                 // anchors per image (9*64*64)
#define NTHR   128                   // threads per block = anchors per block
#define NBLK   2304                  // (8 * 36864) / 128  = 9 blocks/CU exactly
#define BLKS_PER_IMG 288
#define KI     5                     // float4 per thread per chunk
#define F4_PER_CHUNK (KI * NTHR)     // 640
#define NCHUNK 4                     // 20 f4/thread total

// Anchor W/H computed in double (matches Python float arithmetic), cast to f32.
__device__ __constant__ float c_aw[9] = {
    (float)(32.0 * 1.0    * 1.0), (float)(32.0 * 1.0    * 1.4), (float)(32.0 * 1.0    * 0.7),
    (float)(32.0 * 1.2599 * 1.0), (float)(32.0 * 1.2599 * 1.4), (float)(32.0 * 1.2599 * 0.7),
    (float)(32.0 * 1.5874 * 1.0), (float)(32.0 * 1.5874 * 1.4), (float)(32.0 * 1.5874 * 0.7)};
__device__ __constant__ float c_ah[9] = {
    (float)(32.0 * 1.0    * 1.0), (float)(32.0 * 1.0    * 0.7), (float)(32.0 * 1.0    * 1.4),
    (float)(32.0 * 1.2599 * 1.0), (float)(32.0 * 1.2599 * 0.7), (float)(32.0 * 1.2599 * 1.4),
    (float)(32.0 * 1.5874 * 1.0), (float)(32.0 * 1.5874 * 0.7), (float)(32.0 * 1.5874 * 1.4)};

#define LOG2E 1.4426950408889634f
#define LN2   0.6931471805599453f

// Load chunk C (5 coalesced float4 per thread) into named register array BUF.
#define LOADC(BUF, C)                                                           \
    _Pragma("unroll")                                                           \
    for (int k = 0; k < KI; ++k)                                                \
        BUF[k] = base[(C) * F4_PER_CHUNK + k * NTHR + tid];

// BCE over chunk C held in BUF. Accumulates lmax, l2, hot.
#define BCEC(BUF, C)                                                            \
    _Pragma("unroll")                                                           \
    for (int k = 0; k < KI; ++k) {                                              \
        const int e  = (C) * F4_PER_CHUNK + k * NTHR + tid;                     \
        const int la = e / 20;                                                  \
        const int c0 = (e - la * 20) * 4;                                       \
        const int fl = s_flag[la];                                              \
        const float4 x = BUF[k];                                                \
        const float m = (fl >= 0) ? 1.0f : 0.0f;                                \
        const float t0 = __builtin_amdgcn_exp2f(fabsf(x.x) * -LOG2E);           \
        const float t1 = __builtin_amdgcn_exp2f(fabsf(x.y) * -LOG2E);           \
        const float t2 = __builtin_amdgcn_exp2f(fabsf(x.z) * -LOG2E);           \
        const float t3 = __builtin_amdgcn_exp2f(fabsf(x.w) * -LOG2E);           \
        const float g0 = __builtin_amdgcn_logf(1.0f + t0);                      \
        const float g1 = __builtin_amdgcn_logf(1.0f + t1);                      \
        const float g2 = __builtin_amdgcn_logf(1.0f + t2);                      \
        const float g3 = __builtin_amdgcn_logf(1.0f + t3);                      \
        l2   += m * ((g0 + g1) + (g2 + g3));                                    \
        lmax += m * ((fmaxf(x.x, 0.0f) + fmaxf(x.y, 0.0f)) +                    \
                     (fmaxf(x.z, 0.0f) + fmaxf(x.w, 0.0f)));                    \
        if (__any(fl >= 0 && fl < NCLS)) {   /* positive anchors are rare */    \
            hot += (fl == c0    ) ? x.x : 0.0f;                                 \
            hot += (fl == c0 + 1) ? x.y : 0.0f;                                 \
            hot += (fl == c0 + 2) ? x.z : 0.0f;                                 \
            hot += (fl == c0 + 3) ? x.w : 0.0f;                                 \
        }                                                                       \
    }

// One float4 partial per block: {cls_loss, xywh_loss, pos_count, 0}
__global__ __launch_bounds__(NTHR, 5) void retina_main(
    const float* __restrict__ t_xywh,      // [B, N, 4]
    const float* __restrict__ cls_logits,  // [B, N, 80]
    const float* __restrict__ gt_bboxes,   // [B, 32, 4] cxcywh
    const int*   __restrict__ gt_cats,     // [B, 32]
    float4* __restrict__ part)             // [NBLK]
{
    __shared__ int   s_flag[NTHR];
    __shared__ float s_red[2 * 3];

    const int tid = threadIdx.x;
    const int blk = blockIdx.x;
    const int b   = blk / BLKS_PER_IMG;

    const float4* base = (const float4*)cls_logits + (size_t)blk * (NTHR * NCLS / 4);

    // ---- chunk 0 in flight; IoU below hides its latency ----
    float4 A[KI], Bv[KI];
    LOADC(A, 0)

    // ---- anchor geometry: thread tid owns anchor tid of this block ----
    const int n  = (blk % BLKS_PER_IMG) * NTHR + tid;  // anchor within image
    const int a  = n >> 12;
    const int hy = (n >> 6) & 63;
    const int wx = n & 63;
    const float acx = (wx + 0.5f) * 8.0f;
    const float acy = (hy + 0.5f) * 8.0f;
    const float aw  = c_aw[a];
    const float ah  = c_ah[a];

    // ---- IoU vs 32 GTs (wave-uniform scalar GT loads), bit-exact vs numpy ----
    const float4* gt4  = (const float4*)gt_bboxes + b * NGT;
    const int*    gcat = gt_cats + b * NGT;
    float best = -1.0f;
    int   bi   = 0;
    {
#pragma clang fp contract(off)
        const float a_tlx = acx - aw * 0.5f, a_tly = acy - ah * 0.5f;
        const float a_brx = acx + aw * 0.5f, a_bry = acy + ah * 0.5f;
        const float area_a = aw * ah;
        for (int gg = 0; gg < NGT; ++gg) {
            const float4 gb = gt4[gg];               // uniform -> s_load
            const float g_tlx = gb.x - gb.z * 0.5f, g_tly = gb.y - gb.w * 0.5f;
            const float g_brx = gb.x + gb.z * 0.5f, g_bry = gb.y + gb.w * 0.5f;
            float dx = fminf(a_brx, g_brx) - fmaxf(a_tlx, g_tlx);
            float dy = fminf(a_bry, g_bry) - fmaxf(a_tly, g_tly);
            dx = fmaxf(dx, 0.0f);
            dy = fmaxf(dy, 0.0f);
            const float inter = dx * dy;
            const float area_g = gb.z * gb.w;
            const float uni = area_a + area_g - inter;   // no fma
            const float iou = inter / uni;
            if (iou > best) { best = iou; bi = gg; }     // strict > = first argmax
        }
    }

    const bool pos = best > 0.5f;
    const bool neg = best < 0.4f;
    int f = (pos | neg) ? 256 : -1;

    // ---- xywh loss: positives only (rare); gather matched GT lazily ----
    float lx = 0.0f, pcnt = 0.0f;
    if (pos) {
        f    = gcat[bi];                      // per-lane gather, rare lanes
        pcnt = 1.0f;
        const float4 g = gt4[bi];
        const float4 t = ((const float4*)t_xywh)[(size_t)blk * NTHR + tid];
        const float tx = (g.x - acx) / aw;
        const float ty = (g.y - acy) / ah;
        const float tw = logf(g.z / aw + 1e-8f);
        const float th = logf(g.w / ah + 1e-8f);
        const float d0 = t.x - tx, d1 = t.y - ty, d2 = t.z - tw, d3 = t.w - th;
        lx = d0 * d0 + d1 * d1 + d2 * d2 + d3 * d3;
    }
    s_flag[tid] = f;
    __syncthreads();    // drains only chunk 0 (already complete after IoU)

    // ---- software-pipelined BCE: consume chunk c while chunk c+1 loads ----
    float l2 = 0.0f, lmax = 0.0f, hot = 0.0f;
    LOADC(Bv, 1)
    BCEC(A, 0)
    LOADC(A, 2)
    BCEC(Bv, 1)
    LOADC(Bv, 3)
    BCEC(A, 2)
    BCEC(Bv, 3)
    const float lc = lmax + LN2 * l2 - hot;

    // ---- block reduction of (lc, lx, pcnt) across 2 waves ----
    float v0 = lc, v1 = lx, v2 = pcnt;
    for (int o = 32; o > 0; o >>= 1) {
        v0 += __shfl_down(v0, o);
        v1 += __shfl_down(v1, o);
        v2 += __shfl_down(v2, o);
    }
    const int wave = tid >> 6;
    if ((tid & 63) == 0) {
        s_red[wave * 3 + 0] = v0;
        s_red[wave * 3 + 1] = v1;
        s_red[wave * 3 + 2] = v2;
    }
    __syncthreads();
    if (tid == 0) {
        part[blk] = make_float4(s_red[0] + s_red[3],
                                s_red[1] + s_red[4],
                                s_red[2] + s_red[5], 0.0f);
    }
}

// ---- fold 2304 block partials into the scalar loss ----
__global__ __launch_bounds__(256) void retina_final(
    const float4* __restrict__ part, float* __restrict__ out)
{
    __shared__ float s_lc[NB], s_pc[NB], s_lx[NB];
    const int tid = threadIdx.x;
    const int b = tid >> 5, l = tid & 31;    // 32 lanes per image

    float lc = 0.0f, lx = 0.0f, pc = 0.0f;
    for (int i = l; i < BLKS_PER_IMG; i += 32) {
        const float4 p = part[b * BLKS_PER_IMG + i];
        lc += p.x; lx += p.y; pc += p.z;
    }
    for (int o = 16; o > 0; o >>= 1) {       // xor butterfly stays within the 32-group
        lc += __shfl_xor(lc, o);
        lx += __shfl_xor(lx, o);
        pc += __shfl_xor(pc, o);
    }
    if (l == 0) { s_lc[b] = lc; s_pc[b] = pc; s_lx[b] = lx; }
    __syncthreads();

    if (tid == 0) {
        float s = 0.0f, lxt = 0.0f;
        for (int bb = 0; bb < NB; ++bb) {
            lxt += s_lx[bb];
            s   += s_lc[bb] / (s_pc[bb] + 1.0f);
        }
        out[0] = (lxt + s) / (float)NB;
    }
}

extern "C" void kernel_launch(void* const* d_in, const int* in_sizes, int n_in,
                              void* d_out, int out_size, void* d_ws, size_t ws_size,
                              hipStream_t stream)
{
    const float* t_xywh     = (const float*)d_in[0];
    const float* cls_logits = (const float*)d_in[1];
    const float* gt_bboxes  = (const float*)d_in[2];
    const int*   gt_cats    = (const int*)d_in[3];

    float4* part = (float4*)d_ws;   // 2304 * 16 B = 36.9 KB

    retina_main<<<NBLK, NTHR, 0, stream>>>(t_xywh, cls_logits, gt_bboxes, gt_cats, part);
    retina_final<<<1, 256, 0, stream>>>(part, (float*)d_out);
}

// Round 8
// 27.691 us; speedup vs baseline: 1.2628x; 1.2628x over previous
//
#include <hip/hip_runtime.h>

#define NCLS   80
#define NB     8
#define NGT    32
#define NANCH  36864                 // anchors per image (9*64*64)
#define BLK_A  128                   // anchors per block
#define NTHR   256
#define NBLK   2304                  // 8 blocks/CU resident at 32 waves/CU
#define BLKS_PER_IMG 288
#define KI     10                    // float4 per thread, streamed in-loop

#define LOG2E 1.4426950408889634f
#define LN2   0.6931471805599453f

// Anchor W/H computed in double (matches Python float arithmetic), cast to f32.
__device__ __constant__ float c_aw[9] = {
    (float)(32.0 * 1.0    * 1.0), (float)(32.0 * 1.0    * 1.4), (float)(32.0 * 1.0    * 0.7),
    (float)(32.0 * 1.2599 * 1.0), (float)(32.0 * 1.2599 * 1.4), (float)(32.0 * 1.2599 * 0.7),
    (float)(32.0 * 1.5874 * 1.0), (float)(32.0 * 1.5874 * 1.4), (float)(32.0 * 1.5874 * 0.7)};
__device__ __constant__ float c_ah[9] = {
    (float)(32.0 * 1.0    * 1.0), (float)(32.0 * 1.0    * 0.7), (float)(32.0 * 1.0    * 1.4),
    (float)(32.0 * 1.2599 * 1.0), (float)(32.0 * 1.2599 * 0.7), (float)(32.0 * 1.2599 * 1.4),
    (float)(32.0 * 1.5874 * 1.0), (float)(32.0 * 1.5874 * 0.7), (float)(32.0 * 1.5874 * 1.4)};

// One float4 partial per block: {cls_loss(l2 units), xywh_loss, pos_count, 0}
__global__ __launch_bounds__(NTHR, 8) void retina_main(
    const float* __restrict__ t_xywh,      // [B, N, 4]
    const float* __restrict__ cls_logits,  // [B, N, 80]
    const float* __restrict__ gt_bboxes,   // [B, 32, 4] cxcywh
    const int*   __restrict__ gt_cats,     // [B, 32]
    float4* __restrict__ part)             // [NBLK]
{
    __shared__ float s_best[NTHR];
    __shared__ int   s_bi[NTHR];
    __shared__ int   s_flag[BLK_A];   // -1: skip; 0..79: pos class; 256: neg-only
    __shared__ float s_red[4 * 3];

    const int tid = threadIdx.x;
    const int blk = blockIdx.x;
    const int b   = blk / BLKS_PER_IMG;
    const int la0 = tid & (BLK_A - 1);     // anchor owned for IoU
    const int gh  = tid >> 7;              // GT half: 0 -> 0..15, 1 -> 16..31

    // ---- anchor geometry ----
    const int n  = (blk % BLKS_PER_IMG) * BLK_A + la0;   // anchor within image
    const int a  = n >> 12;
    const int hy = (n >> 6) & 63;
    const int wx = n & 63;
    const float acx = (wx + 0.5f) * 8.0f;
    const float acy = (hy + 0.5f) * 8.0f;
    const float aw  = c_aw[a];
    const float ah  = c_ah[a];

    const float4* gt4  = (const float4*)gt_bboxes + b * NGT;
    const int*    gcat = gt_cats + b * NGT;

    // ---- IoU vs 16 GTs per thread (split across thread halves) ----
    float best = -1.0f;
    int   bi   = 0;
    {
        const float a_tlx = acx - aw * 0.5f, a_tly = acy - ah * 0.5f;
        const float a_brx = acx + aw * 0.5f, a_bry = acy + ah * 0.5f;
        const float area_a = aw * ah;
        const int g0 = gh * 16;
        for (int j = 0; j < 16; ++j) {
            const int gg = g0 + j;
            const float4 gb = gt4[gg];               // wave-uniform -> s_load
            const float g_tlx = gb.x - gb.z * 0.5f, g_tly = gb.y - gb.w * 0.5f;
            const float g_brx = gb.x + gb.z * 0.5f, g_bry = gb.y + gb.w * 0.5f;
            float dx = fminf(a_brx, g_brx) - fmaxf(a_tlx, g_tlx);
            float dy = fminf(a_bry, g_bry) - fmaxf(a_tly, g_tly);
            dx = fmaxf(dx, 0.0f);
            dy = fmaxf(dy, 0.0f);
            const float inter = dx * dy;
            const float uni   = area_a + gb.z * gb.w - inter;
            const float iou   = inter * __builtin_amdgcn_rcpf(uni);  // ~2ulp; ok vs 294 thr
            if (iou > best) { best = iou; bi = gg; }   // strict > = first argmax
        }
    }
    s_best[tid] = best;
    s_bi[tid]   = bi;
    __syncthreads();

    // ---- combine halves (first-half priority on ties), flags, xywh loss ----
    float lx = 0.0f, pcnt = 0.0f;
    if (tid < BLK_A) {
        const float bhi = s_best[tid + BLK_A];
        if (bhi > best) { best = bhi; bi = s_bi[tid + BLK_A]; }
        const bool pos = best > 0.5f;
        const bool neg = best < 0.4f;
        int f = (pos | neg) ? 256 : -1;
        if (pos) {                                // rare (~0.4% of anchors)
            f    = gcat[bi];
            pcnt = 1.0f;
            const float4 g = gt4[bi];
            const float4 t = ((const float4*)t_xywh)[(size_t)b * NANCH + n];
            const float tx = (g.x - acx) / aw;
            const float ty = (g.y - acy) / ah;
            const float tw = logf(g.z / aw + 1e-8f);
            const float th = logf(g.w / ah + 1e-8f);
            const float d0 = t.x - tx, d1 = t.y - ty, d2 = t.z - tw, d3 = t.w - th;
            lx = d0 * d0 + d1 * d1 + d2 * d2 + d3 * d3;
        }
        s_flag[tid] = f;
    }
    __syncthreads();   // nothing in flight to drain; streaming loads start AFTER this

    // ---- streaming BCE: softplus(x) = ln2 * log2(1 + 2^(x*log2e)); |x|<~6 so safe ----
    const float4* base = (const float4*)cls_logits + (size_t)blk * (BLK_A * NCLS / 4);
    float l2 = 0.0f, hot = 0.0f;
#pragma unroll
    for (int k = 0; k < KI; ++k) {
        const int e  = k * NTHR + tid;       // f4 index within block slice
        const int la = e / 20;               // owning anchor (20 f4 per anchor)
        const float4 x = base[e];
        const int fl = s_flag[la];
        const float t0 = __builtin_amdgcn_exp2f(x.x * LOG2E);
        const float t1 = __builtin_amdgcn_exp2f(x.y * LOG2E);
        const float t2 = __builtin_amdgcn_exp2f(x.z * LOG2E);
        const float t3 = __builtin_amdgcn_exp2f(x.w * LOG2E);
        const float g0 = __builtin_amdgcn_logf(1.0f + t0);
        const float g1 = __builtin_amdgcn_logf(1.0f + t1);
        const float g2 = __builtin_amdgcn_logf(1.0f + t2);
        const float g3 = __builtin_amdgcn_logf(1.0f + t3);
        const float m  = (fl >= 0) ? 1.0f : 0.0f;
        l2 += m * ((g0 + g1) + (g2 + g3));
        if (__any((unsigned)fl < NCLS)) {    // positive anchors are rare
            const int c0 = (e - la * 20) * 4;
            hot += (fl == c0    ) ? x.x : 0.0f;
            hot += (fl == c0 + 1) ? x.y : 0.0f;
            hot += (fl == c0 + 2) ? x.z : 0.0f;
            hot += (fl == c0 + 3) ? x.w : 0.0f;
        }
    }
    const float lc = LN2 * l2 - hot;

    // ---- block reduction of (lc, lx, pcnt) ----
    float v0 = lc, v1 = lx, v2 = pcnt;
    for (int o = 32; o > 0; o >>= 1) {
        v0 += __shfl_down(v0, o);
        v1 += __shfl_down(v1, o);
        v2 += __shfl_down(v2, o);
    }
    const int wave = tid >> 6;
    if ((tid & 63) == 0) {
        s_red[wave * 3 + 0] = v0;
        s_red[wave * 3 + 1] = v1;
        s_red[wave * 3 + 2] = v2;
    }
    __syncthreads();
    if (tid == 0) {
        float c = 0.0f, xw = 0.0f, pc = 0.0f;
        for (int w2 = 0; w2 < 4; ++w2) {
            c  += s_red[w2 * 3 + 0];
            xw += s_red[w2 * 3 + 1];
            pc += s_red[w2 * 3 + 2];
        }
        part[blk] = make_float4(c, xw, pc, 0.0f);
    }
}

// ---- fold 2304 block partials into the scalar loss ----
__global__ __launch_bounds__(256) void retina_final(
    const float4* __restrict__ part, float* __restrict__ out)
{
    __shared__ float s_lc[NB], s_pc[NB], s_lx[NB];
    const int tid = threadIdx.x;
    const int b = tid >> 5, l = tid & 31;    // 32 lanes per image

    float lc = 0.0f, lx = 0.0f, pc = 0.0f;
    for (int i = l; i < BLKS_PER_IMG; i += 32) {
        const float4 p = part[b * BLKS_PER_IMG + i];
        lc += p.x; lx += p.y; pc += p.z;
    }
    for (int o = 16; o > 0; o >>= 1) {       // xor butterfly stays within the 32-group
        lc += __shfl_xor(lc, o);
        lx += __shfl_xor(lx, o);
        pc += __shfl_xor(pc, o);
    }
    if (l == 0) { s_lc[b] = lc; s_pc[b] = pc; s_lx[b] = lx; }
    __syncthreads();

    if (tid == 0) {
        float s = 0.0f, lxt = 0.0f;
        for (int bb = 0; bb < NB; ++bb) {
            lxt += s_lx[bb];
            s   += s_lc[bb] / (s_pc[bb] + 1.0f);
        }
        out[0] = (lxt + s) / (float)NB;
    }
}

extern "C" void kernel_launch(void* const* d_in, const int* in_sizes, int n_in,
                              void* d_out, int out_size, void* d_ws, size_t ws_size,
                              hipStream_t stream)
{
    const float* t_xywh     = (const float*)d_in[0];
    const float* cls_logits = (const float*)d_in[1];
    const float* gt_bboxes  = (const float*)d_in[2];
    const int*   gt_cats    = (const int*)d_in[3];

    float4* part = (float4*)d_ws;   // 2304 * 16 B = 36.9 KB

    retina_main<<<NBLK, NTHR, 0, stream>>>(t_xywh, cls_logits, gt_bboxes, gt_cats, part);
    retina_final<<<1, 256, 0, stream>>>(part, (float*)d_out);
}